// Round 1
// baseline (1105.834 us; speedup 1.0000x reference)
//
#include <hip/hip_runtime.h>
#include <hip/hip_bf16.h>
#include <stdint.h>
#include <stddef.h>

// Problem constants
#define B_   16384
#define M_   3
#define D_   2048
#define DH_  1024
#define DV_  512
#define ROWS (B_ * M_)      // 49152
#define RT_ROWS 126         // rows per GEMM row-tile (42 whole batches)
#define RT_BATCH 42
#define NRT 391             // ceil(49152/126)
#define NHT 16              // h-tiles of 64

typedef _Float16 f16;
typedef f16   f16x8 __attribute__((ext_vector_type(8)));
typedef float f32x4 __attribute__((ext_vector_type(4)));

__device__ __forceinline__ void async16(const void* g, void* l) {
  __builtin_amdgcn_global_load_lds(
      (const __attribute__((address_space(1))) void*)g,
      (__attribute__((address_space(3))) void*)l, 16, 0, 0);
}

// ---- kernel 1: wvf[d] = sum_v Wfc[v] * Wv[v][d]  (grid 64, block 256) ---
__global__ void k_wvf(const float* __restrict__ Wv, const float* __restrict__ Wfc,
                      float* __restrict__ wvf) {
  int dl = threadIdx.x & 31;
  int vs = threadIdx.x >> 5;
  int d = blockIdx.x * 32 + dl;
  float acc = 0.f;
  #pragma unroll 8
  for (int v = vs * 64; v < vs * 64 + 64; ++v)
    acc += Wfc[v] * Wv[(size_t)v * D_ + d];
  __shared__ float red[8][32];
  red[vs][dl] = acc;
  __syncthreads();
  if (threadIdx.x < 32) {
    float s = 0.f;
    #pragma unroll
    for (int i = 0; i < 8; ++i) s += red[i][threadIdx.x];
    wvf[blockIdx.x * 32 + threadIdx.x] = s;
  }
}

// ---- kernel 2: Wh[j][d] fp16; j<1024 -> Wq[j], else Wk[j-1024] ----------
__global__ void k_castw(const float* __restrict__ Wq, const float* __restrict__ Wk,
                        f16* __restrict__ Wh) {
  int t = blockIdx.x * 256 + threadIdx.x;
  int idx = t * 8;
  int j = idx >> 11;
  int d = idx & (D_ - 1);
  const float* src = (j < DH_) ? (Wq + (size_t)j * D_ + d)
                               : (Wk + (size_t)(j - DH_) * D_ + d);
  f32x4 a = *(const f32x4*)src;
  f32x4 b = *(const f32x4*)(src + 4);
  f16x8 h;
  h[0] = (f16)a[0]; h[1] = (f16)a[1]; h[2] = (f16)a[2]; h[3] = (f16)a[3];
  h[4] = (f16)b[0]; h[5] = (f16)b[1]; h[6] = (f16)b[2]; h[7] = (f16)b[3];
  *(f16x8*)(Wh + (size_t)idx) = h;
}

// ---- kernel 3: Xh = fp16(x), vf[row] = x_row . wvf ----------------------
__global__ void k_prep(const float* __restrict__ x, const float* __restrict__ wvf,
                       f16* __restrict__ Xh, float* __restrict__ vf) {
  int w = threadIdx.x >> 6, lane = threadIdx.x & 63;
  int row = blockIdx.x * 4 + w;
  const float* xr = x + (size_t)row * D_;
  f16* xo = Xh + (size_t)row * D_;
  float acc = 0.f;
  #pragma unroll
  for (int p = 0; p < 4; ++p) {
    int col = p * 512 + lane * 8;
    f32x4 a = *(const f32x4*)(xr + col);
    f32x4 b = *(const f32x4*)(xr + col + 4);
    f32x4 wa = *(const f32x4*)(wvf + col);
    f32x4 wb = *(const f32x4*)(wvf + col + 4);
    f16x8 h;
    h[0] = (f16)a[0]; h[1] = (f16)a[1]; h[2] = (f16)a[2]; h[3] = (f16)a[3];
    h[4] = (f16)b[0]; h[5] = (f16)b[1]; h[6] = (f16)b[2]; h[7] = (f16)b[3];
    *(f16x8*)(xo + col) = h;
    acc += a[0]*wa[0] + a[1]*wa[1] + a[2]*wa[2] + a[3]*wa[3]
         + b[0]*wb[0] + b[1]*wb[1] + b[2]*wb[2] + b[3]*wb[3];
  }
  #pragma unroll
  for (int off = 1; off < 64; off <<= 1) acc += __shfl_xor(acc, off);
  if (lane == 0) vf[row] = acc;
}

// ---- kernel 4: fused GEMM + partial Gram --------------------------------
// Block (ht, rt): 126 rows (42 batches) x paired 64 q-cols + 64 k-cols at
// h in [ht*64, ht*64+64). BK=64, swizzled LDS (slot = chunk ^ (row&7)).
// NEW: double-buffered LDS (2x32 KB), 2-phase pipeline — stage K-tile t+1
// at top of iteration t, compute tile t, then one s_waitcnt vmcnt(0) + raw
// s_barrier per K-step (issue-early / wait-late; no per-step full drain
// before compute). setprio(1) around MFMA clusters.
// Epilogue: q/k halves -> LDS buffer 0, 42x9 partial Gram dots over 64 h,
// write S_part[(ht*9+ij)][b] (transposed for coalesced k_final reads).
__global__ __launch_bounds__(256, 2) void k_gemm(const f16* __restrict__ Xh,
                                                 const f16* __restrict__ Wh,
                                                 float* __restrict__ S_part) {
  const int ht = blockIdx.x;   // 0..15  h-tile
  const int rt = blockIdx.y;   // 0..390 row tile (126 rows each)
  const int tid = threadIdx.x;
  const int w = tid >> 6, lane = tid & 63;
  const int wr = w >> 1, wc = w & 1;

  __shared__ __align__(16) f16 lds_a[2][128 * 64];   // A staging (dbuf) / q epilogue
  __shared__ __align__(16) f16 lds_b[2][128 * 64];   // B staging (dbuf) / k epilogue
  const int BUF = 128 * 64;                           // f16 elements per buffer

  f32x4 acc[4][4] = {};

  // staging: 4 issues/wave for A + 4 for B; each issue = 8 rows x 128 B.
  // lane l -> row (l>>3) within issue, LDS slot l&7; source chunk (l&7)^row.
  const int srow = lane >> 3;
  const int schunk = (lane & 7) ^ srow;
  const int scol = schunk * 8;

  const f16* gA[4]; const f16* gB[4];
  f16 *la[4], *lb[4];
  #pragma unroll
  for (int t = 0; t < 4; ++t) {
    int rowT = w * 32 + t * 8;                 // tile-local row 0..127
    int ra = rt * RT_ROWS + rowT + srow;       // global X row (2-row overlap)
    if (ra > ROWS - 1) ra = ROWS - 1;
    gA[t] = Xh + (size_t)ra * D_ + scol;
    int c = rowT + srow;                       // tile col index for B
    int rb = (c < 64) ? (ht * 64 + c) : (DH_ + ht * 64 + (c - 64));
    gB[t] = Wh + (size_t)rb * D_ + scol;
    la[t] = &lds_a[0][rowT * 64];
    lb[t] = &lds_b[0][rowT * 64];
  }

  // fragment reads: row m=lane&15, k-quad kq=lane>>4; slot (s*4+kq)^(m&7)
  const int m = lane & 15;
  const int kq = lane >> 4;
  const f16* fa0 = &lds_a[0][(size_t)(wr * 64 + m) * 64 + ((kq    ) ^ (m & 7)) * 8];
  const f16* fa1 = &lds_a[0][(size_t)(wr * 64 + m) * 64 + ((kq + 4) ^ (m & 7)) * 8];
  const f16* fb0 = &lds_b[0][(size_t)(wc * 64 + m) * 64 + ((kq    ) ^ (m & 7)) * 8];
  const f16* fb1 = &lds_b[0][(size_t)(wc * 64 + m) * 64 + ((kq + 4) ^ (m & 7)) * 8];

  // ---- prologue: stage K-tile 0 into buffer 0, full drain, barrier
  #pragma unroll
  for (int t = 0; t < 4; ++t) async16(gA[t], la[t]);
  #pragma unroll
  for (int t = 0; t < 4; ++t) async16(gB[t], lb[t]);
  asm volatile("s_waitcnt vmcnt(0)" ::: "memory");
  __builtin_amdgcn_s_barrier();

  int cur = 0;
  for (int k0 = 64; k0 <= D_; k0 += 64) {
    const int nxt = cur ^ 1;
    // issue next tile's staging FIRST (flies during compute below)
    if (k0 < D_) {
      #pragma unroll
      for (int t = 0; t < 4; ++t) async16(gA[t] + k0, la[t] + nxt * BUF);
      #pragma unroll
      for (int t = 0; t < 4; ++t) async16(gB[t] + k0, lb[t] + nxt * BUF);
    }
    const int co = cur * BUF;
    {
      f16x8 af[4], bf[4];
      #pragma unroll
      for (int i = 0; i < 4; ++i) af[i] = *(const f16x8*)(fa0 + co + i * 16 * 64);
      #pragma unroll
      for (int j = 0; j < 4; ++j) bf[j] = *(const f16x8*)(fb0 + co + j * 16 * 64);
      __builtin_amdgcn_s_setprio(1);
      #pragma unroll
      for (int i = 0; i < 4; ++i)
        #pragma unroll
        for (int j = 0; j < 4; ++j)
          acc[i][j] = __builtin_amdgcn_mfma_f32_16x16x32_f16(af[i], bf[j], acc[i][j], 0, 0, 0);
      __builtin_amdgcn_s_setprio(0);
    }
    {
      f16x8 af[4], bf[4];
      #pragma unroll
      for (int i = 0; i < 4; ++i) af[i] = *(const f16x8*)(fa1 + co + i * 16 * 64);
      #pragma unroll
      for (int j = 0; j < 4; ++j) bf[j] = *(const f16x8*)(fb1 + co + j * 16 * 64);
      __builtin_amdgcn_s_setprio(1);
      #pragma unroll
      for (int i = 0; i < 4; ++i)
        #pragma unroll
        for (int j = 0; j < 4; ++j)
          acc[i][j] = __builtin_amdgcn_mfma_f32_16x16x32_f16(af[i], bf[j], acc[i][j], 0, 0, 0);
      __builtin_amdgcn_s_setprio(0);
    }
    // wait-late: drain this iteration's staging (had the whole compute
    // phase to fly), pin everything, single barrier per K-step.
    asm volatile("s_waitcnt vmcnt(0)" ::: "memory");
    __builtin_amdgcn_sched_barrier(0);
    __builtin_amdgcn_s_barrier();
    cur = nxt;
  }

  // ---- epilogue: stash q/k halves in LDS buffer 0, layout [row 0..127][h 0..63]
  __syncthreads();   // hard drain before repurposing staging buffers
  {
    f16* dst = wc ? &lds_b[0][0] : &lds_a[0][0];
    const int rbase = wr * 64 + (lane >> 4) * 4;
    const int hcol = lane & 15;
    #pragma unroll
    for (int i = 0; i < 4; ++i)
      #pragma unroll
      for (int j = 0; j < 4; ++j)
        #pragma unroll
        for (int r = 0; r < 4; ++r)
          dst[(size_t)(rbase + i * 16 + r) * 64 + j * 16 + hcol] = (f16)acc[i][j][r];
  }
  __syncthreads();

  // ---- 42 batches x 9 pairs, 64-length dots, write S_part[(ht*9+ij)][b]
  for (int p = tid; p < RT_BATCH * 9; p += 256) {
    int bl = p / 9;
    int ij = p - bl * 9;
    int i = ij / 3, j = ij - i * 3;
    const f16* qp = &lds_a[0][(size_t)(bl * 3 + i) * 64];
    const f16* kp = &lds_b[0][(size_t)(bl * 3 + j) * 64];
    float s = 0.f;
    #pragma unroll
    for (int hc = 0; hc < 8; ++hc) {
      f16x8 qa = *(const f16x8*)(qp + hc * 8);
      f16x8 ka = *(const f16x8*)(kp + hc * 8);
      #pragma unroll
      for (int t = 0; t < 8; ++t) s += (float)qa[t] * (float)ka[t];
    }
    int b = rt * RT_BATCH + bl;
    if (b < B_) S_part[(size_t)(ht * 9 + ij) * B_ + b] = s;
  }
}

// ---- kernel 5: reduce h-chunks, softmax, apply vf  (thread/batch) -------
// S_part is [144][B_] -> all 144 loads fully coalesced across threads.
__global__ void k_final(const float* __restrict__ S_part, const float* __restrict__ vf,
                        float* __restrict__ out) {
  int b = blockIdx.x * 256 + threadIdx.x;
  float s[9] = {0,0,0,0,0,0,0,0,0};
  #pragma unroll
  for (int ht = 0; ht < NHT; ++ht)
    #pragma unroll
    for (int ij = 0; ij < 9; ++ij) s[ij] += S_part[(size_t)(ht * 9 + ij) * B_ + b];
  float attn[3] = {0.f, 0.f, 0.f};
  #pragma unroll
  for (int i = 0; i < 3; ++i) {
    float m = fmaxf(s[i*3+0], fmaxf(s[i*3+1], s[i*3+2]));
    float e0 = __expf(s[i*3+0] - m), e1 = __expf(s[i*3+1] - m), e2 = __expf(s[i*3+2] - m);
    float inv = 1.f / (e0 + e1 + e2);
    attn[0] += e0 * inv; attn[1] += e1 * inv; attn[2] += e2 * inv;
  }
  float o = attn[0] * vf[b * 3 + 0] + attn[1] * vf[b * 3 + 1] + attn[2] * vf[b * 3 + 2];
  out[b] = o * (1.f / 3.f);
}

extern "C" void kernel_launch(void* const* d_in, const int* in_sizes, int n_in,
                              void* d_out, int out_size, void* d_ws, size_t ws_size,
                              hipStream_t stream) {
  const float* x   = (const float*)d_in[0];
  const float* Wq  = (const float*)d_in[1];
  const float* Wk  = (const float*)d_in[2];
  const float* Wv  = (const float*)d_in[3];
  const float* Wfc = (const float*)d_in[4];
  float* out = (float*)d_out;

  char* ws = (char*)d_ws;
  f16*   Xh     = (f16*)(ws);                        // 201326592 B
  f16*   Wh     = (f16*)(ws + 201326592ull);         // 8388608 B
  float* wvf    = (float*)(ws + 209715200ull);       // 8192 B
  float* vf     = (float*)(ws + 209723392ull);       // 196608 B
  float* S_part = (float*)(ws + 209920000ull);       // 144*16384*4 = 9437184 B

  k_wvf  <<<64,              256, 0, stream>>>(Wv, Wfc, wvf);
  k_castw<<<2048,            256, 0, stream>>>(Wq, Wk, Wh);
  k_prep <<<ROWS / 4,        256, 0, stream>>>(x, wvf, Xh, vf);
  k_gemm <<<dim3(NHT, NRT),  256, 0, stream>>>(Xh, Wh, S_part);
  k_final<<<B_ / 256,        256, 0, stream>>>(S_part, vf, out);
}

// Round 2
// 1095.512 us; speedup vs baseline: 1.0094x; 1.0094x over previous
//
#include <hip/hip_runtime.h>
#include <hip/hip_bf16.h>
#include <stdint.h>
#include <stddef.h>

// Problem constants
#define B_   16384
#define M_   3
#define D_   2048
#define DH_  1024
#define DV_  512
#define ROWS (B_ * M_)      // 49152
#define RT_ROWS 126         // rows per GEMM row-tile (42 whole batches)
#define RT_BATCH 42
#define NRT 391             // ceil(49152/126)
#define NHT 16              // h-tiles of 64

typedef _Float16 f16;
typedef f16   f16x8 __attribute__((ext_vector_type(8)));
typedef float f32x4 __attribute__((ext_vector_type(4)));

__device__ __forceinline__ void async16(const void* g, void* l) {
  __builtin_amdgcn_global_load_lds(
      (const __attribute__((address_space(1))) void*)g,
      (__attribute__((address_space(3))) void*)l, 16, 0, 0);
}

// ---- kernel 1: wvf[d] = sum_v Wfc[v] * Wv[v][d]  (grid 64, block 256) ---
__global__ void k_wvf(const float* __restrict__ Wv, const float* __restrict__ Wfc,
                      float* __restrict__ wvf) {
  int dl = threadIdx.x & 31;
  int vs = threadIdx.x >> 5;
  int d = blockIdx.x * 32 + dl;
  float acc = 0.f;
  #pragma unroll 8
  for (int v = vs * 64; v < vs * 64 + 64; ++v)
    acc += Wfc[v] * Wv[(size_t)v * D_ + d];
  __shared__ float red[8][32];
  red[vs][dl] = acc;
  __syncthreads();
  if (threadIdx.x < 32) {
    float s = 0.f;
    #pragma unroll
    for (int i = 0; i < 8; ++i) s += red[i][threadIdx.x];
    wvf[blockIdx.x * 32 + threadIdx.x] = s;
  }
}

// ---- kernel 2: Wh[j][d] fp16; j<1024 -> Wq[j], else Wk[j-1024] ----------
__global__ void k_castw(const float* __restrict__ Wq, const float* __restrict__ Wk,
                        f16* __restrict__ Wh) {
  int t = blockIdx.x * 256 + threadIdx.x;
  int idx = t * 8;
  int j = idx >> 11;
  int d = idx & (D_ - 1);
  const float* src = (j < DH_) ? (Wq + (size_t)j * D_ + d)
                               : (Wk + (size_t)(j - DH_) * D_ + d);
  f32x4 a = *(const f32x4*)src;
  f32x4 b = *(const f32x4*)(src + 4);
  f16x8 h;
  h[0] = (f16)a[0]; h[1] = (f16)a[1]; h[2] = (f16)a[2]; h[3] = (f16)a[3];
  h[4] = (f16)b[0]; h[5] = (f16)b[1]; h[6] = (f16)b[2]; h[7] = (f16)b[3];
  *(f16x8*)(Wh + (size_t)idx) = h;
}

// ---- kernel 3: Xh = fp16(x), vf[row] = x_row . wvf ----------------------
__global__ void k_prep(const float* __restrict__ x, const float* __restrict__ wvf,
                       f16* __restrict__ Xh, float* __restrict__ vf) {
  int w = threadIdx.x >> 6, lane = threadIdx.x & 63;
  int row = blockIdx.x * 4 + w;
  const float* xr = x + (size_t)row * D_;
  f16* xo = Xh + (size_t)row * D_;
  float acc = 0.f;
  #pragma unroll
  for (int p = 0; p < 4; ++p) {
    int col = p * 512 + lane * 8;
    f32x4 a = *(const f32x4*)(xr + col);
    f32x4 b = *(const f32x4*)(xr + col + 4);
    f32x4 wa = *(const f32x4*)(wvf + col);
    f32x4 wb = *(const f32x4*)(wvf + col + 4);
    f16x8 h;
    h[0] = (f16)a[0]; h[1] = (f16)a[1]; h[2] = (f16)a[2]; h[3] = (f16)a[3];
    h[4] = (f16)b[0]; h[5] = (f16)b[1]; h[6] = (f16)b[2]; h[7] = (f16)b[3];
    *(f16x8*)(xo + col) = h;
    acc += a[0]*wa[0] + a[1]*wa[1] + a[2]*wa[2] + a[3]*wa[3]
         + b[0]*wb[0] + b[1]*wb[1] + b[2]*wb[2] + b[3]*wb[3];
  }
  #pragma unroll
  for (int off = 1; off < 64; off <<= 1) acc += __shfl_xor(acc, off);
  if (lane == 0) vf[row] = acc;
}

// ---- kernel 4: fused GEMM + partial Gram --------------------------------
// Round-0 structure (128x128 tile, 2.6 blocks/CU) but BK=32 with DOUBLE
// buffering at CONSTANT 32 KB LDS: per K-step, issue next tile's 4 staging
// loads FIRST, compute 16 MFMA from current buffer (~180 cyc cover for the
// mostly-L2-hit loads), then one vmcnt(0) + raw s_barrier. TLP preserved.
// Swizzle: 4 chunks/row XOR (m&3) plus physical-row-pair involution
// p = m ^ ((m>>2)&1), applied on BOTH the pre-swizzled global source and
// the fragment reads (both-sides-or-neither) -> free 2-way bank pattern.
// Epilogue unchanged: q/k halves -> LDS, 42x9 partial Gram dots over 64 h,
// write S_part[(ht*9+ij)][b] (transposed for coalesced k_final).
__global__ __launch_bounds__(256, 3) void k_gemm(const f16* __restrict__ Xh,
                                                 const f16* __restrict__ Wh,
                                                 float* __restrict__ S_part) {
  const int ht = blockIdx.x;   // 0..15  h-tile
  const int rt = blockIdx.y;   // 0..390 row tile (126 rows each)
  const int tid = threadIdx.x;
  const int w = tid >> 6, lane = tid & 63;
  const int wr = w >> 1, wc = w & 1;

  __shared__ __align__(16) f16 lds_a[2][128 * 32];   // A dbuf / q epilogue
  __shared__ __align__(16) f16 lds_b[2][128 * 32];   // B dbuf / k epilogue
  const int BUF = 128 * 32;                          // 4096 f16 per buffer

  f32x4 acc[4][4] = {};

  // ---- staging geometry (BK=32): per wave 2 issues/operand, 16 rows x 64 B
  // lane l -> physical row p = w*32 + t*16 + (l>>2), dest chunk l&3 (linear).
  // Stored content: logical row m = p ^ ((p>>2)&1); source chunk (l&3)^(m&3).
  const int srow16 = lane >> 2;
  const int pchunk = lane & 3;

  const f16* gA[2]; const f16* gB[2];
  f16 *la[2], *lb[2];
  #pragma unroll
  for (int t = 0; t < 2; ++t) {
    int p = w * 32 + t * 16 + srow16;          // physical tile row 0..127
    int m = p ^ ((p >> 2) & 1);                // logical tile row
    int c = pchunk ^ (m & 3);                  // pre-swizzled source chunk
    int ra = rt * RT_ROWS + m;                 // global X row (2-row overlap)
    if (ra > ROWS - 1) ra = ROWS - 1;
    gA[t] = Xh + (size_t)ra * D_ + c * 8;
    int rb = (m < 64) ? (ht * 64 + m) : (DH_ + ht * 64 + (m - 64));
    gB[t] = Wh + (size_t)rb * D_ + c * 8;
    la[t] = &lds_a[0][(w * 32 + t * 16) * 32];
    lb[t] = &lds_b[0][(w * 32 + t * 16) * 32];
  }

  // ---- fragment reads: logical row m = base + i*16, m&3 == lane&3,
  // physical frow = m ^ ((lane>>2)&1); chunk slot = kq ^ (lane&3).
  const int kq = lane >> 4;                               // 0..3, 8 k each
  const int e  = (lane >> 2) & 1;
  const int frow_a = (wr * 64 + (lane & 15)) ^ e;
  const int frow_b = (wc * 64 + (lane & 15)) ^ e;
  const int slot = (kq ^ (lane & 3)) * 8;
  const f16* fa = &lds_a[0][frow_a * 32 + slot];
  const f16* fb = &lds_b[0][frow_b * 32 + slot];

  // ---- prologue: stage K-tile 0 into buffer 0, drain, barrier
  #pragma unroll
  for (int t = 0; t < 2; ++t) { async16(gA[t], la[t]); async16(gB[t], lb[t]); }
  asm volatile("s_waitcnt vmcnt(0)" ::: "memory");
  __builtin_amdgcn_s_barrier();

  for (int s = 0; s < 64; ++s) {
    const int cur = s & 1, nxt = cur ^ 1;
    // issue next tile's staging FIRST (flies under the MFMA below)
    if (s < 63) {
      const int koff = (s + 1) * 32;
      #pragma unroll
      for (int t = 0; t < 2; ++t) {
        async16(gA[t] + koff, la[t] + nxt * BUF);
        async16(gB[t] + koff, lb[t] + nxt * BUF);
      }
    }
    __builtin_amdgcn_sched_barrier(0);   // keep issues ahead of compute
    {
      const int co = cur * BUF;
      f16x8 af[4], bf[4];
      #pragma unroll
      for (int i = 0; i < 4; ++i) af[i] = *(const f16x8*)(fa + co + i * 512);
      #pragma unroll
      for (int j = 0; j < 4; ++j) bf[j] = *(const f16x8*)(fb + co + j * 512);
      #pragma unroll
      for (int i = 0; i < 4; ++i)
        #pragma unroll
        for (int j = 0; j < 4; ++j)
          acc[i][j] = __builtin_amdgcn_mfma_f32_16x16x32_f16(af[i], bf[j], acc[i][j], 0, 0, 0);
    }
    // wait-late: this iteration's staging had the whole compute to fly
    asm volatile("s_waitcnt vmcnt(0)" ::: "memory");
    __builtin_amdgcn_sched_barrier(0);
    __builtin_amdgcn_s_barrier();
  }

  // ---- epilogue: stash q/k halves in LDS (f16), layout [row 0..127][h 0..63]
  __syncthreads();
  {
    f16* dst = wc ? &lds_b[0][0] : &lds_a[0][0];
    const int rbase = wr * 64 + (lane >> 4) * 4;
    const int hcol = lane & 15;
    #pragma unroll
    for (int i = 0; i < 4; ++i)
      #pragma unroll
      for (int j = 0; j < 4; ++j)
        #pragma unroll
        for (int r = 0; r < 4; ++r)
          dst[(size_t)(rbase + i * 16 + r) * 64 + j * 16 + hcol] = (f16)acc[i][j][r];
  }
  __syncthreads();

  // ---- 42 batches x 9 pairs, 64-length dots, write S_part[(ht*9+ij)][b]
  for (int p = tid; p < RT_BATCH * 9; p += 256) {
    int bl = p / 9;
    int ij = p - bl * 9;
    int i = ij / 3, j = ij - i * 3;
    const f16* qp = &lds_a[0][(size_t)(bl * 3 + i) * 64];
    const f16* kp = &lds_b[0][(size_t)(bl * 3 + j) * 64];
    float s = 0.f;
    #pragma unroll
    for (int hc = 0; hc < 8; ++hc) {
      f16x8 qa = *(const f16x8*)(qp + hc * 8);
      f16x8 ka = *(const f16x8*)(kp + hc * 8);
      #pragma unroll
      for (int t = 0; t < 8; ++t) s += (float)qa[t] * (float)ka[t];
    }
    int b = rt * RT_BATCH + bl;
    if (b < B_) S_part[(size_t)(ht * 9 + ij) * B_ + b] = s;
  }
}

// ---- kernel 5: reduce h-chunks, softmax, apply vf  (thread/batch) -------
// S_part is [144][B_] -> all 144 loads fully coalesced across threads.
__global__ void k_final(const float* __restrict__ S_part, const float* __restrict__ vf,
                        float* __restrict__ out) {
  int b = blockIdx.x * 256 + threadIdx.x;
  float s[9] = {0,0,0,0,0,0,0,0,0};
  #pragma unroll
  for (int ht = 0; ht < NHT; ++ht)
    #pragma unroll
    for (int ij = 0; ij < 9; ++ij) s[ij] += S_part[(size_t)(ht * 9 + ij) * B_ + b];
  float attn[3] = {0.f, 0.f, 0.f};
  #pragma unroll
  for (int i = 0; i < 3; ++i) {
    float m = fmaxf(s[i*3+0], fmaxf(s[i*3+1], s[i*3+2]));
    float e0 = __expf(s[i*3+0] - m), e1 = __expf(s[i*3+1] - m), e2 = __expf(s[i*3+2] - m);
    float inv = 1.f / (e0 + e1 + e2);
    attn[0] += e0 * inv; attn[1] += e1 * inv; attn[2] += e2 * inv;
  }
  float o = attn[0] * vf[b * 3 + 0] + attn[1] * vf[b * 3 + 1] + attn[2] * vf[b * 3 + 2];
  out[b] = o * (1.f / 3.f);
}

extern "C" void kernel_launch(void* const* d_in, const int* in_sizes, int n_in,
                              void* d_out, int out_size, void* d_ws, size_t ws_size,
                              hipStream_t stream) {
  const float* x   = (const float*)d_in[0];
  const float* Wq  = (const float*)d_in[1];
  const float* Wk  = (const float*)d_in[2];
  const float* Wv  = (const float*)d_in[3];
  const float* Wfc = (const float*)d_in[4];
  float* out = (float*)d_out;

  char* ws = (char*)d_ws;
  f16*   Xh     = (f16*)(ws);                        // 201326592 B
  f16*   Wh     = (f16*)(ws + 201326592ull);         // 8388608 B
  float* wvf    = (float*)(ws + 209715200ull);       // 8192 B
  float* vf     = (float*)(ws + 209723392ull);       // 196608 B
  float* S_part = (float*)(ws + 209920000ull);       // 144*16384*4 = 9437184 B

  k_wvf  <<<64,              256, 0, stream>>>(Wv, Wfc, wvf);
  k_castw<<<2048,            256, 0, stream>>>(Wq, Wk, Wh);
  k_prep <<<ROWS / 4,        256, 0, stream>>>(x, wvf, Xh, vf);
  k_gemm <<<dim3(NHT, NRT),  256, 0, stream>>>(Xh, Wh, S_part);
  k_final<<<B_ / 256,        256, 0, stream>>>(S_part, vf, out);
}

// Round 3
// 1015.874 us; speedup vs baseline: 1.0886x; 1.0784x over previous
//
#include <hip/hip_runtime.h>
#include <hip/hip_bf16.h>
#include <stdint.h>
#include <stddef.h>

// Problem constants
#define B_   16384
#define M_   3
#define D_   2048
#define DH_  1024
#define DV_  512
#define ROWS (B_ * M_)      // 49152
#define RT_ROWS 126         // rows per GEMM row-tile (42 whole batches)
#define RT_BATCH 42
#define NRT 391             // ceil(49152/126)
#define NHT 16              // h-tiles of 64
#define NWG (NHT * NRT)     // 6256 = 8 * 782 exactly -> simple swizzle bijective
#define NXCD 8

typedef _Float16 f16;
typedef f16   f16x8 __attribute__((ext_vector_type(8)));
typedef float f32x4 __attribute__((ext_vector_type(4)));

__device__ __forceinline__ void async16(const void* g, void* l) {
  __builtin_amdgcn_global_load_lds(
      (const __attribute__((address_space(1))) void*)g,
      (__attribute__((address_space(3))) void*)l, 16, 0, 0);
}

// ---- kernel 1: wvf[d] = sum_v Wfc[v] * Wv[v][d]  (grid 64, block 256) ---
__global__ void k_wvf(const float* __restrict__ Wv, const float* __restrict__ Wfc,
                      float* __restrict__ wvf) {
  int dl = threadIdx.x & 31;
  int vs = threadIdx.x >> 5;
  int d = blockIdx.x * 32 + dl;
  float acc = 0.f;
  #pragma unroll 8
  for (int v = vs * 64; v < vs * 64 + 64; ++v)
    acc += Wfc[v] * Wv[(size_t)v * D_ + d];
  __shared__ float red[8][32];
  red[vs][dl] = acc;
  __syncthreads();
  if (threadIdx.x < 32) {
    float s = 0.f;
    #pragma unroll
    for (int i = 0; i < 8; ++i) s += red[i][threadIdx.x];
    wvf[blockIdx.x * 32 + threadIdx.x] = s;
  }
}

// ---- kernel 2: Wh[j][d] fp16; j<1024 -> Wq[j], else Wk[j-1024] ----------
__global__ void k_castw(const float* __restrict__ Wq, const float* __restrict__ Wk,
                        f16* __restrict__ Wh) {
  int t = blockIdx.x * 256 + threadIdx.x;
  int idx = t * 8;
  int j = idx >> 11;
  int d = idx & (D_ - 1);
  const float* src = (j < DH_) ? (Wq + (size_t)j * D_ + d)
                               : (Wk + (size_t)(j - DH_) * D_ + d);
  f32x4 a = *(const f32x4*)src;
  f32x4 b = *(const f32x4*)(src + 4);
  f16x8 h;
  h[0] = (f16)a[0]; h[1] = (f16)a[1]; h[2] = (f16)a[2]; h[3] = (f16)a[3];
  h[4] = (f16)b[0]; h[5] = (f16)b[1]; h[6] = (f16)b[2]; h[7] = (f16)b[3];
  *(f16x8*)(Wh + (size_t)idx) = h;
}

// ---- kernel 3: Xh = fp16(x), vf[row] = x_row . wvf ----------------------
__global__ void k_prep(const float* __restrict__ x, const float* __restrict__ wvf,
                       f16* __restrict__ Xh, float* __restrict__ vf) {
  int w = threadIdx.x >> 6, lane = threadIdx.x & 63;
  int row = blockIdx.x * 4 + w;
  const float* xr = x + (size_t)row * D_;
  f16* xo = Xh + (size_t)row * D_;
  float acc = 0.f;
  #pragma unroll
  for (int p = 0; p < 4; ++p) {
    int col = p * 512 + lane * 8;
    f32x4 a = *(const f32x4*)(xr + col);
    f32x4 b = *(const f32x4*)(xr + col + 4);
    f32x4 wa = *(const f32x4*)(wvf + col);
    f32x4 wb = *(const f32x4*)(wvf + col + 4);
    f16x8 h;
    h[0] = (f16)a[0]; h[1] = (f16)a[1]; h[2] = (f16)a[2]; h[3] = (f16)a[3];
    h[4] = (f16)b[0]; h[5] = (f16)b[1]; h[6] = (f16)b[2]; h[7] = (f16)b[3];
    *(f16x8*)(xo + col) = h;
    acc += a[0]*wa[0] + a[1]*wa[1] + a[2]*wa[2] + a[3]*wa[3]
         + b[0]*wb[0] + b[1]*wb[1] + b[2]*wb[2] + b[3]*wb[3];
  }
  #pragma unroll
  for (int off = 1; off < 64; off <<= 1) acc += __shfl_xor(acc, off);
  if (lane == 0) vf[row] = acc;
}

// ---- kernel 4: fused GEMM + partial Gram --------------------------------
// Round-0 proven body (single-buffer BK=64, 2x __syncthreads per K-step,
// 32 KB LDS, ~2.6 blocks/CU) with ONE change: XCD-chunked block swizzle.
// Grid is 1D (6256 blocks). Default dispatch round-robins XCDs, so the 16
// ht-blocks sharing one 516 KB A-panel land on 8 different L2s -> 4.2x
// HBM over-fetch (856 MB measured vs 210 MB minimal). Chunked bijective
// remap (6256 = 8*782) gives each XCD contiguous wgids: all 16 ht-blocks
// of a panel on one XCD, panels fetched ~once, Wh L3-resident. Staging
// loads shift HBM->L2 latency, shortening the per-K-step drain stall.
// Epilogue: q/k halves -> LDS, 42x9 partial Gram dots over 64 h,
// write S_part[(ht*9+ij)][b] (transposed for coalesced k_final).
__global__ __launch_bounds__(256, 3) void k_gemm(const f16* __restrict__ Xh,
                                                 const f16* __restrict__ Wh,
                                                 float* __restrict__ S_part) {
  // XCD-chunked bijective swizzle: dispatch d -> XCD d%8; give XCD x the
  // contiguous wgid range [x*782, (x+1)*782).
  const int wgid = (blockIdx.x & (NXCD - 1)) * (NWG / NXCD) + (blockIdx.x >> 3);
  const int ht = wgid & (NHT - 1);   // 0..15  h-tile (fast within a panel)
  const int rt = wgid >> 4;          // 0..390 row tile (126 rows each)
  const int tid = threadIdx.x;
  const int w = tid >> 6, lane = tid & 63;
  const int wr = w >> 1, wc = w & 1;

  __shared__ __align__(16) f16 lds_a[128 * 64];   // A staging / q epilogue
  __shared__ __align__(16) f16 lds_b[128 * 64];   // B staging / k epilogue

  f32x4 acc[4][4] = {};

  // staging: 4 issues/wave for A + 4 for B; each issue = 8 rows x 128 B.
  // lane l -> row (l>>3) within issue, LDS slot l&7; source chunk (l&7)^row.
  const int srow = lane >> 3;
  const int schunk = (lane & 7) ^ srow;
  const int scol = schunk * 8;

  const f16* gA[4]; const f16* gB[4];
  f16 *la[4], *lb[4];
  #pragma unroll
  for (int t = 0; t < 4; ++t) {
    int rowT = w * 32 + t * 8;                 // tile-local row 0..127
    int ra = rt * RT_ROWS + rowT + srow;       // global X row (2-row overlap)
    if (ra > ROWS - 1) ra = ROWS - 1;
    gA[t] = Xh + (size_t)ra * D_ + scol;
    int c = rowT + srow;                       // tile col index for B
    int rb = (c < 64) ? (ht * 64 + c) : (DH_ + ht * 64 + (c - 64));
    gB[t] = Wh + (size_t)rb * D_ + scol;
    la[t] = &lds_a[rowT * 64];
    lb[t] = &lds_b[rowT * 64];
  }

  // fragment reads: row m=lane&15, k-quad kq=lane>>4; slot (s*4+kq)^(m&7)
  const int m = lane & 15;
  const int kq = lane >> 4;
  const f16* fa0 = &lds_a[(size_t)(wr * 64 + m) * 64 + ((kq    ) ^ (m & 7)) * 8];
  const f16* fa1 = &lds_a[(size_t)(wr * 64 + m) * 64 + ((kq + 4) ^ (m & 7)) * 8];
  const f16* fb0 = &lds_b[(size_t)(wc * 64 + m) * 64 + ((kq    ) ^ (m & 7)) * 8];
  const f16* fb1 = &lds_b[(size_t)(wc * 64 + m) * 64 + ((kq + 4) ^ (m & 7)) * 8];

  for (int k0 = 0; k0 < D_; k0 += 64) {
    #pragma unroll
    for (int t = 0; t < 4; ++t) async16(gA[t] + k0, la[t]);
    #pragma unroll
    for (int t = 0; t < 4; ++t) async16(gB[t] + k0, lb[t]);
    __syncthreads();
    {
      f16x8 af[4], bf[4];
      #pragma unroll
      for (int i = 0; i < 4; ++i) af[i] = *(const f16x8*)(fa0 + i * 16 * 64);
      #pragma unroll
      for (int j = 0; j < 4; ++j) bf[j] = *(const f16x8*)(fb0 + j * 16 * 64);
      #pragma unroll
      for (int i = 0; i < 4; ++i)
        #pragma unroll
        for (int j = 0; j < 4; ++j)
          acc[i][j] = __builtin_amdgcn_mfma_f32_16x16x32_f16(af[i], bf[j], acc[i][j], 0, 0, 0);
    }
    {
      f16x8 af[4], bf[4];
      #pragma unroll
      for (int i = 0; i < 4; ++i) af[i] = *(const f16x8*)(fa1 + i * 16 * 64);
      #pragma unroll
      for (int j = 0; j < 4; ++j) bf[j] = *(const f16x8*)(fb1 + j * 16 * 64);
      #pragma unroll
      for (int i = 0; i < 4; ++i)
        #pragma unroll
        for (int j = 0; j < 4; ++j)
          acc[i][j] = __builtin_amdgcn_mfma_f32_16x16x32_f16(af[i], bf[j], acc[i][j], 0, 0, 0);
    }
    __syncthreads();
  }

  // ---- epilogue: stash q/k halves in LDS (f16), layout [row 0..127][h 0..63]
  {
    f16* dst = wc ? lds_b : lds_a;
    const int rbase = wr * 64 + (lane >> 4) * 4;
    const int hcol = lane & 15;
    #pragma unroll
    for (int i = 0; i < 4; ++i)
      #pragma unroll
      for (int j = 0; j < 4; ++j)
        #pragma unroll
        for (int r = 0; r < 4; ++r)
          dst[(size_t)(rbase + i * 16 + r) * 64 + j * 16 + hcol] = (f16)acc[i][j][r];
  }
  __syncthreads();

  // ---- 42 batches x 9 pairs, 64-length dots, write S_part[(ht*9+ij)][b]
  for (int p = tid; p < RT_BATCH * 9; p += 256) {
    int bl = p / 9;
    int ij = p - bl * 9;
    int i = ij / 3, j = ij - i * 3;
    const f16* qp = &lds_a[(size_t)(bl * 3 + i) * 64];
    const f16* kp = &lds_b[(size_t)(bl * 3 + j) * 64];
    float s = 0.f;
    #pragma unroll
    for (int hc = 0; hc < 8; ++hc) {
      f16x8 qa = *(const f16x8*)(qp + hc * 8);
      f16x8 ka = *(const f16x8*)(kp + hc * 8);
      #pragma unroll
      for (int t = 0; t < 8; ++t) s += (float)qa[t] * (float)ka[t];
    }
    int b = rt * RT_BATCH + bl;
    if (b < B_) S_part[(size_t)(ht * 9 + ij) * B_ + b] = s;
  }
}

// ---- kernel 5: reduce h-chunks, softmax, apply vf  (thread/batch) -------
// S_part is [144][B_] -> all 144 loads fully coalesced across threads.
__global__ void k_final(const float* __restrict__ S_part, const float* __restrict__ vf,
                        float* __restrict__ out) {
  int b = blockIdx.x * 256 + threadIdx.x;
  float s[9] = {0,0,0,0,0,0,0,0,0};
  #pragma unroll
  for (int ht = 0; ht < NHT; ++ht)
    #pragma unroll
    for (int ij = 0; ij < 9; ++ij) s[ij] += S_part[(size_t)(ht * 9 + ij) * B_ + b];
  float attn[3] = {0.f, 0.f, 0.f};
  #pragma unroll
  for (int i = 0; i < 3; ++i) {
    float m = fmaxf(s[i*3+0], fmaxf(s[i*3+1], s[i*3+2]));
    float e0 = __expf(s[i*3+0] - m), e1 = __expf(s[i*3+1] - m), e2 = __expf(s[i*3+2] - m);
    float inv = 1.f / (e0 + e1 + e2);
    attn[0] += e0 * inv; attn[1] += e1 * inv; attn[2] += e2 * inv;
  }
  float o = attn[0] * vf[b * 3 + 0] + attn[1] * vf[b * 3 + 1] + attn[2] * vf[b * 3 + 2];
  out[b] = o * (1.f / 3.f);
}

extern "C" void kernel_launch(void* const* d_in, const int* in_sizes, int n_in,
                              void* d_out, int out_size, void* d_ws, size_t ws_size,
                              hipStream_t stream) {
  const float* x   = (const float*)d_in[0];
  const float* Wq  = (const float*)d_in[1];
  const float* Wk  = (const float*)d_in[2];
  const float* Wv  = (const float*)d_in[3];
  const float* Wfc = (const float*)d_in[4];
  float* out = (float*)d_out;

  char* ws = (char*)d_ws;
  f16*   Xh     = (f16*)(ws);                        // 201326592 B
  f16*   Wh     = (f16*)(ws + 201326592ull);         // 8388608 B
  float* wvf    = (float*)(ws + 209715200ull);       // 8192 B
  float* vf     = (float*)(ws + 209723392ull);       // 196608 B
  float* S_part = (float*)(ws + 209920000ull);       // 144*16384*4 = 9437184 B

  k_wvf  <<<64,              256, 0, stream>>>(Wv, Wfc, wvf);
  k_castw<<<2048,            256, 0, stream>>>(Wq, Wk, Wh);
  k_prep <<<ROWS / 4,        256, 0, stream>>>(x, wvf, Xh, vf);
  k_gemm <<<NWG,             256, 0, stream>>>(Xh, Wh, S_part);
  k_final<<<B_ / 256,        256, 0, stream>>>(S_part, vf, out);
}